// Round 9
// baseline (227.876 us; speedup 1.0000x reference)
//
#include <hip/hip_runtime.h>
#include <hip/hip_fp16.h>
#include <stdint.h>
#include <math.h>

#define BS    2
#define RAYS  514
#define NS    64
#define LSEQ  512
#define NF    257
#define HIDN  64
#define SPLIT 4
#define JC    16
#define NBLK  512

#define TWO_PI_F 6.28318530717958647692f

__device__ __forceinline__ uint32_t rotl32(uint32_t x, int d){ return (x<<d)|(x>>(32-d)); }

__device__ __forceinline__ void tf_rounds4(uint32_t& x0, uint32_t& x1, int a, int b, int c, int d){
  x0+=x1; x1=rotl32(x1,a); x1^=x0;
  x0+=x1; x1=rotl32(x1,b); x1^=x0;
  x0+=x1; x1=rotl32(x1,c); x1^=x0;
  x0+=x1; x1=rotl32(x1,d); x1^=x0;
}

// Threefry-2x32, 20 rounds, matching jax._src.prng.threefry2x32
__device__ void threefry2x32(uint32_t k0, uint32_t k1, uint32_t x0, uint32_t x1,
                             uint32_t& o0, uint32_t& o1)
{
  const uint32_t ks2 = k0 ^ k1 ^ 0x1BD11BDAu;
  x0 += k0; x1 += k1;
  tf_rounds4(x0,x1,13,15,26,6);   x0+=k1;  x1+=ks2+1u;
  tf_rounds4(x0,x1,17,29,16,24);  x0+=ks2; x1+=k0+2u;
  tf_rounds4(x0,x1,13,15,26,6);   x0+=k0;  x1+=k1+3u;
  tf_rounds4(x0,x1,17,29,16,24);  x0+=k1;  x1+=ks2+4u;
  tf_rounds4(x0,x1,13,15,26,6);   x0+=ks2; x1+=k0+5u;
  o0 = x0; o1 = x1;
}

// Reproduces _ray_directions() for ray r (verified round 0).
__device__ void ray_dir(int r, float d[3])
{
  if (r >= 512) { d[0]=0.f; d[1]=0.f; d[2] = (r==512) ? 1.0f : -1.0f; return; }
  int i = r >> 4, j = r & 15;
  uint32_t o0, o1;
  threefry2x32(0u, 42u, 0u, (uint32_t)i, o0, o1);
  uint32_t bits = o0 ^ o1;
  float u = __uint_as_float((bits >> 9) | 0x3F800000u) - 1.0f;   // uniform [0,1)
  const float step = TWO_PI_F / 32.0f;
  float a = (float)i * step + step * u;
  float e = acosf(2.0f * ((float)(j+1) * (1.0f/17.0f)) - 1.0f);
  float se = sinf(e);
  d[0] = cosf(a) * se;
  d[1] = sinf(a) * se;
  d[2] = cosf(e);
}

__device__ __forceinline__ float dval(int s){ return ((float)s*(1.0f/63.0f))*7.9f + 0.1f; }

__device__ __forceinline__ uint32_t pk2(float a, float b){
  return (uint32_t)__half_as_ushort(__float2half(a)) |
         ((uint32_t)__half_as_ushort(__float2half(b)) << 16);
}

// Grid-wide barrier: all NBLK blocks co-resident (LDS 56.5KB -> 2 blocks/CU,
// __launch_bounds__(256,2)). Generation-counter scheme; agent-scope atomics
// (cross-XCD coherent) + threadfence for data visibility.
__device__ __forceinline__ void grid_barrier(int* counter, int* generation)
{
  __syncthreads();
  if (threadIdx.x == 0){
    __threadfence();    // release: flush this XCD's writes to coherence point
    int gen = __hip_atomic_load(generation, __ATOMIC_ACQUIRE, __HIP_MEMORY_SCOPE_AGENT);
    int arrived = __hip_atomic_fetch_add(counter, 1, __ATOMIC_ACQ_REL, __HIP_MEMORY_SCOPE_AGENT) + 1;
    if (arrived == NBLK){
      __hip_atomic_store(counter, 0, __ATOMIC_RELAXED, __HIP_MEMORY_SCOPE_AGENT);
      __hip_atomic_fetch_add(generation, 1, __ATOMIC_RELEASE, __HIP_MEMORY_SCOPE_AGENT);
    } else {
      while (__hip_atomic_load(generation, __ATOMIC_ACQUIRE, __HIP_MEMORY_SCOPE_AGENT) == gen)
        __builtin_amdgcn_s_sleep(2);
    }
    __threadfence();    // acquire: invalidate L1/L2 so we see other XCDs' data
  }
  __syncthreads();
}

// Single-launch pipeline: A (per-ray MLP+weights) -> bar -> B (delay-bucket
// scan + W_sig dot into g) -> bar -> C (DFT + frac phase into out).
__global__ __launch_bounds__(256, 2)
void mono(const float* __restrict__ rays_o, const float* __restrict__ position_tx,
          const float* __restrict__ W1, const float* __restrict__ b1,
          const float* __restrict__ w_attn,
          const float* __restrict__ W_sig, const float* __restrict__ b_sig,
          __half* __restrict__ wh, float* __restrict__ w_arr, int* __restrict__ delay_arr,
          float* __restrict__ g, float* __restrict__ out, int* __restrict__ bar)
{
  __shared__ __align__(16) char smem[56464];
  const int tid = threadIdx.x;

  // ---------------- Phase A: rays (waves 0..1027 of 2048) ----------------
  { // zero atomic accumulators (131072 threads cover g:65536, out:1028)
    int gi = blockIdx.x*256 + tid;
    if (gi < BS*NS*LSEQ) g[gi] = 0.f;
    if (gi < BS*NF*2) out[gi] = 0.f;
  }
  {
    const int wid = tid >> 6, lane = tid & 63;     // lane = s index
    const int br = blockIdx.x*4 + wid;
    if (br < BS*RAYS){
      const int b = br / RAYS, r = br % RAYS;
      float dir[3]; ray_dir(r, dir);
      const float mn[3] = {-5.f,-5.f,-3.f}, mx[3] = {5.f,5.f,3.f};
      float ro[3], ntx[3];
      #pragma unroll
      for (int c=0;c<3;c++){
        ro[c] = rays_o[b*3+c];
        float t = position_tx[b*3+c];
        ntx[c] = 2.0f*(t - mn[c])/(mx[c]-mn[c]) - 1.0f;
      }
      const float dv = dval(lane);
      float feat[9], dd2 = 0.f;
      #pragma unroll
      for (int c=0;c<3;c++){
        float pt = ro[c] + dir[c]*dv;
        float npt = 2.0f*(pt - mn[c])/(mx[c]-mn[c]) - 1.0f;
        float ddc = ((ntx[c]-npt) + 1.0f)/2.0f*(mx[c]-mn[c]) + mn[c];
        dd2 += ddc*ddc;
        feat[c]   = npt;
        feat[3+c] = -dir[c];
        feat[6+c] = ntx[c];
      }
      float h[HIDN];
      float av = 0.f;
      #pragma unroll
      for (int j=0; j<HIDN; j++){
        float hj = b1[j];
        #pragma unroll
        for (int f=0; f<9; f++) hj = fmaf(feat[f], W1[f*HIDN + j], hj);
        hj = fmaxf(hj, 0.0f);
        h[j] = hj;
        av = fmaf(hj, w_attn[j], av);
      }
      float attn = fmaxf(av, 0.f) + log1pf(expf(-fabsf(av)));   // softplus
      float dist = (lane < NS-1) ? (dval(lane+1) - dv) : 1e10f;
      float alpha = 1.0f - expf(-attn*dist);
      float fac = 1.0f - alpha + 1e-6f;
      float scan = fac;
      #pragma unroll
      for (int m=1; m<64; m<<=1){
        float up = __shfl_up(scan, m, 64);
        if (lane >= m) scan *= up;
      }
      float T = __shfl_up(scan, 1, 64);
      if (lane == 0) T = 1.0f;
      float wgt = T * alpha;

      float delf = fminf(fmaxf(rintf(sqrtf(dd2)*16000.0f/343.0f), 0.f), 511.f);
      const int bsid = b*NS + lane;
      const int o2 = bsid*RAYS + r;
      w_arr[o2] = wgt;
      delay_arr[o2] = (int)delf;
      #pragma unroll
      for (int p=0; p<SPLIT; p++){
        uint4 v0, v1;
        v0.x = pk2(wgt*h[p*16+ 0], wgt*h[p*16+ 1]);
        v0.y = pk2(wgt*h[p*16+ 2], wgt*h[p*16+ 3]);
        v0.z = pk2(wgt*h[p*16+ 4], wgt*h[p*16+ 5]);
        v0.w = pk2(wgt*h[p*16+ 6], wgt*h[p*16+ 7]);
        v1.x = pk2(wgt*h[p*16+ 8], wgt*h[p*16+ 9]);
        v1.y = pk2(wgt*h[p*16+10], wgt*h[p*16+11]);
        v1.z = pk2(wgt*h[p*16+12], wgt*h[p*16+13]);
        v1.w = pk2(wgt*h[p*16+14], wgt*h[p*16+15]);
        uint4* dst = (uint4*)(wh + (((size_t)p*BS*NS + bsid)*RAYS + r)*16);
        dst[0] = v0; dst[1] = v1;
      }
    }
  }

  grid_barrier(&bar[0], &bar[1]);

  // ---------------- Phase B: delay buckets -> g ----------------
  {
    float (*bucket)[JC+1] = (float(*)[JC+1])smem;            // 34,816 B
    float (*part)[JC+1]   = (float(*)[JC+1])(smem + 34816);  //  1,088 B (16 segs)
    uint4* stage4  = (uint4*)(smem + 35904);                 // 16,448 B
    int*   delay_l = (int*)  (smem + 52352);                 //  2,056 B
    float* w_l     = (float*)(smem + 54408);                 //  2,056 B -> 56,464

    const int bsid = blockIdx.x >> 2, p = blockIdx.x & 3;
    const int obase = bsid * RAYS;

    for (int i = tid; i < LSEQ*(JC+1); i += 256) (&bucket[0][0])[i] = 0.f;
    {
      const uint4* whp = (const uint4*)(wh + ((size_t)p*BS*NS + bsid)*RAYS*16);
      for (int i = tid; i < RAYS*2; i += 256) stage4[i] = whp[i];
    }
    for (int i = tid; i < RAYS; i += 256){
      delay_l[i] = delay_arr[obase + i];
      w_l[i] = w_arr[obase + i];
    }
    __syncthreads();

    { // scatter: 16 slices x 16 static cols (<=4-way same-address per wave)
      const int j = tid & 15, slice = tid >> 4;
      const ushort* stage = (const ushort*)stage4;
      for (int r = slice; r < RAYS; r += 16){
        int d = delay_l[r];
        float v = __half2float(__ushort_as_half(stage[r*16 + j]));
        atomicAdd(&bucket[d][j], v);
        if (p == 0 && j == 0) atomicAdd(&bucket[d][JC], w_l[r]);
      }
    }
    __syncthreads();

    // blocked inclusive scan: 16 segs x 32 rows
    const int seg = tid >> 4, col = tid & 15, d0 = seg*32;
    {
      float run = 0.f;
      for (int k2=0;k2<32;k2++){ run += bucket[d0+k2][col]; bucket[d0+k2][col] = run; }
      part[seg][col] = run;
      if (p == 0 && col == 15){
        float rw = 0.f;
        for (int k2=0;k2<32;k2++){ rw += bucket[d0+k2][JC]; bucket[d0+k2][JC] = rw; }
        part[seg][JC] = rw;
      }
    }
    __syncthreads();
    {
      float off = 0.f;
      for (int t=0;t<seg;t++) off += part[t][col];
      for (int k2=0;k2<32;k2++) bucket[d0+k2][col] += off;
      if (p == 0 && col == 15){
        float ow = 0.f;
        for (int t=0;t<seg;t++) ow += part[t][JC];
        for (int k2=0;k2<32;k2++) bucket[d0+k2][JC] += ow;
      }
    }
    __syncthreads();

    // dot + mask + path loss -> atomicAdd into g[bsid][l]
    const int s = bsid % NS;
    const float dv = dval(s);
    const float shiftf = rintf((16000.0f*dv)/343.0f);
    const int shift = (int)shiftf;
    const int jbase = p*JC;
    for (int l = tid; l < LSEQ; l += 256){
      float mt = (((float)(LSEQ-1-l)) - shiftf > 0.f) ? 1.f : 0.f;
      if (mt > 0.f){
        float acc = 0.f;
        #pragma unroll
        for (int jj=0;jj<JC;jj++) acc += bucket[l][jj] * W_sig[(jbase+jj)*LSEQ + l];
        if (p == 0) acc += b_sig[l] * bucket[l][JC];
        int pli = shift + l;
        if (pli < 4) pli = 5;                   // path_loss[:4] = path_loss[5]
        float ideal = ((float)pli/16000.0f)*343.0f;
        atomicAdd(&g[bsid*LSEQ + l], acc / (ideal + 0.001f));
      }
    }
  }

  grid_barrier(&bar[0], &bar[1]);

  // ---------------- Phase C: DFT + fractional phase -> out ----------------
  {
    float4* gs4 = (float4*)smem;                       // 2,048 B
    float (*red)[64][2] = (float(*)[64][2])(smem + 2048); // 2,048 B

    const int bsid = blockIdx.x >> 2, grp = blockIdx.x & 3;
    const int b = bsid / NS, s = bsid % NS;

    if (tid < LSEQ/4) gs4[tid] = ((const float4*)(g + bsid*LSEQ))[tid];
    __syncthreads();

    const int c = tid >> 6, bl = tid & 63;             // c = l-chunk wave, bl = bin
    const int k = grp*64 + bl;
    float re = 0.f, im = 0.f;
    {
      const int l0 = c*128;
      int t0 = (k*l0) & (LSEQ-1);
      float wi, wr; sincosf(-(TWO_PI_F/512.0f)*(float)t0, &wi, &wr);
      float ss, cs; sincosf(-(TWO_PI_F/512.0f)*(float)k,  &ss, &cs);
      for (int q=0; q<32; q++){
        float4 gv = gs4[c*32 + q];                     // wave-uniform broadcast
        #pragma unroll
        for (int e=0; e<4; e++){
          float gvv = (e==0)?gv.x:(e==1)?gv.y:(e==2)?gv.z:gv.w;
          re = fmaf(gvv, wr, re);
          im = fmaf(gvv, wi, im);
          float nr = wr*cs - wi*ss;
          wi = fmaf(wr, ss, wi*cs);
          wr = nr;
        }
      }
    }
    red[c][bl][0] = re; red[c][bl][1] = im;
    __syncthreads();

    const float cfrac = (16000.0f*dval(s))/343.0f;     // fractional pts2rx_idx
    if (tid < 64){
      const int kk = grp*64 + tid;
      float rs = red[0][tid][0] + red[1][tid][0] + red[2][tid][0] + red[3][tid][0];
      float is = red[0][tid][1] + red[1][tid][1] + red[2][tid][1] + red[3][tid][1];
      float ang = -(TWO_PI_F/512.0f)*((float)kk*cfrac);
      float sp, cp; sincosf(ang, &sp, &cp);
      atomicAdd(&out[(b*NF + kk)*2],     rs*cp - is*sp);
      atomicAdd(&out[(b*NF + kk)*2 + 1], rs*sp + is*cp);
    } else if (grp == 0 && tid < 128){
      // bin 256 on wave 1: DFT_256(g) = sum_l (-1)^l g[l] (exact, real)
      int t = tid - 64;
      float4 a = gs4[t], bq = gs4[t+64];
      float alt = (a.x - a.y + a.z - a.w) + (bq.x - bq.y + bq.z - bq.w);
      #pragma unroll
      for (int m=32; m>=1; m>>=1) alt += __shfl_xor(alt, m, 64);
      if (t == 0){
        float ang = -(TWO_PI_F/512.0f)*(256.0f*cfrac);
        float sp, cp; sincosf(ang, &sp, &cp);
        atomicAdd(&out[(b*NF + 256)*2],     alt*cp);
        atomicAdd(&out[(b*NF + 256)*2 + 1], alt*sp);
      }
    }
  }
}

extern "C" void kernel_launch(void* const* d_in, const int* in_sizes, int n_in,
                              void* d_out, int out_size, void* d_ws, size_t ws_size,
                              hipStream_t stream)
{
  const float* rays_o      = (const float*)d_in[0];
  const float* position_tx = (const float*)d_in[1];
  const float* W1          = (const float*)d_in[2];
  const float* b1          = (const float*)d_in[3];
  const float* w_attn      = (const float*)d_in[4];
  const float* W_sig       = (const float*)d_in[5];
  const float* b_sig       = (const float*)d_in[6];
  float* out = (float*)d_out;

  // workspace layout (~9.2 MB total)
  char* ws = (char*)d_ws;
  __half* wh       = (__half*)ws;                               // 4*128*514*16*2B = 8,421,376
  float* w_arr     = (float*)(ws + 8421376);                    // 263,168
  int*   delay_arr = (int*)  (ws + 8421376 + 263168);           // 263,168
  float* g         = (float*)(ws + 8421376 + 2*263168);         // 262,144
  int*   bar       = (int*)  (ws + 8421376 + 2*263168 + 262144);// 8 B

  hipMemsetAsync(bar, 0, 8, stream);
  mono<<<NBLK, 256, 0, stream>>>(rays_o, position_tx, W1, b1, w_attn, W_sig, b_sig,
                                 wh, w_arr, delay_arr, g, out, bar);
}

// Round 10
// 54.615 us; speedup vs baseline: 4.1724x; 4.1724x over previous
//
#include <hip/hip_runtime.h>
#include <hip/hip_fp16.h>
#include <stdint.h>
#include <math.h>

#define BS    2
#define RAYS  514
#define NS    64
#define LSEQ  512
#define NF    257
#define HIDN  64
#define SPLIT 4
#define JC    16      // hidden columns per k2 block

#define TWO_PI_F 6.28318530717958647692f

__device__ __forceinline__ uint32_t rotl32(uint32_t x, int d){ return (x<<d)|(x>>(32-d)); }

__device__ __forceinline__ void tf_rounds4(uint32_t& x0, uint32_t& x1, int a, int b, int c, int d){
  x0+=x1; x1=rotl32(x1,a); x1^=x0;
  x0+=x1; x1=rotl32(x1,b); x1^=x0;
  x0+=x1; x1=rotl32(x1,c); x1^=x0;
  x0+=x1; x1=rotl32(x1,d); x1^=x0;
}

// Threefry-2x32, 20 rounds, matching jax._src.prng.threefry2x32
__device__ void threefry2x32(uint32_t k0, uint32_t k1, uint32_t x0, uint32_t x1,
                             uint32_t& o0, uint32_t& o1)
{
  const uint32_t ks2 = k0 ^ k1 ^ 0x1BD11BDAu;
  x0 += k0; x1 += k1;
  tf_rounds4(x0,x1,13,15,26,6);   x0+=k1;  x1+=ks2+1u;
  tf_rounds4(x0,x1,17,29,16,24);  x0+=ks2; x1+=k0+2u;
  tf_rounds4(x0,x1,13,15,26,6);   x0+=k0;  x1+=k1+3u;
  tf_rounds4(x0,x1,17,29,16,24);  x0+=k1;  x1+=ks2+4u;
  tf_rounds4(x0,x1,13,15,26,6);   x0+=ks2; x1+=k0+5u;
  o0 = x0; o1 = x1;
}

// Reproduces _ray_directions() for ray r (verified round 0).
__device__ void ray_dir(int r, float d[3])
{
  if (r >= 512) { d[0]=0.f; d[1]=0.f; d[2] = (r==512) ? 1.0f : -1.0f; return; }
  int i = r >> 4, j = r & 15;
  uint32_t o0, o1;
  threefry2x32(0u, 42u, 0u, (uint32_t)i, o0, o1);
  uint32_t bits = o0 ^ o1;
  float u = __uint_as_float((bits >> 9) | 0x3F800000u) - 1.0f;   // uniform [0,1)
  const float step = TWO_PI_F / 32.0f;
  float a = (float)i * step + step * u;
  float e = acosf(2.0f * ((float)(j+1) * (1.0f/17.0f)) - 1.0f);
  float se = sinf(e);
  d[0] = cosf(a) * se;
  d[1] = sinf(a) * se;
  d[2] = cosf(e);
}

__device__ __forceinline__ float dval(int s){ return ((float)s*(1.0f/63.0f))*7.9f + 0.1f; }

__device__ __forceinline__ uint32_t pk2(float a, float b){
  return (uint32_t)__half_as_ushort(__float2half(a)) |
         ((uint32_t)__half_as_ushort(__float2half(b)) << 16);
}

// K1: 4 waves/block, one (b,r) per wave; lane = s. Stores wh in the
// p-quartered layout [p][bsid][r][16] so k2's staging loads are contiguous.
// Also zeroes g and out for this replay (stream order covers k2/k3).
__global__ __launch_bounds__(256)
void k1_rays(const float* __restrict__ rays_o, const float* __restrict__ position_tx,
             const float* __restrict__ W1, const float* __restrict__ b1,
             const float* __restrict__ w_attn,
             __half* __restrict__ wh, float* __restrict__ w_arr, int* __restrict__ delay_arr,
             float* __restrict__ g, float* __restrict__ out)
{
  const int tid = threadIdx.x;
  const int wid = tid >> 6, lane = tid & 63;       // lane = s index
  const int br = blockIdx.x*4 + wid;               // 257*4 = 1028 = BS*RAYS
  const int b = br / RAYS, r = br % RAYS;

  { // zero the atomic accumulators (65792 threads cover g:65536 and out:1028)
    int gi = blockIdx.x*256 + tid;
    if (gi < BS*NS*LSEQ) g[gi] = 0.f;
    if (gi < BS*NF*2) out[gi] = 0.f;
  }

  float dir[3]; ray_dir(r, dir);
  const float mn[3] = {-5.f,-5.f,-3.f}, mx[3] = {5.f,5.f,3.f};
  float ro[3], ntx[3];
  #pragma unroll
  for (int c=0;c<3;c++){
    ro[c] = rays_o[b*3+c];
    float t = position_tx[b*3+c];
    ntx[c] = 2.0f*(t - mn[c])/(mx[c]-mn[c]) - 1.0f;
  }

  const float dv = dval(lane);
  float feat[9], dd2 = 0.f;
  #pragma unroll
  for (int c=0;c<3;c++){
    float pt = ro[c] + dir[c]*dv;
    float npt = 2.0f*(pt - mn[c])/(mx[c]-mn[c]) - 1.0f;
    float ddc = ((ntx[c]-npt) + 1.0f)/2.0f*(mx[c]-mn[c]) + mn[c];
    dd2 += ddc*ddc;
    feat[c]   = npt;
    feat[3+c] = -dir[c];
    feat[6+c] = ntx[c];
  }

  float h[HIDN];
  float av = 0.f;
  #pragma unroll
  for (int j=0; j<HIDN; j++){
    float hj = b1[j];
    #pragma unroll
    for (int f=0; f<9; f++) hj = fmaf(feat[f], W1[f*HIDN + j], hj);
    hj = fmaxf(hj, 0.0f);
    h[j] = hj;
    av = fmaf(hj, w_attn[j], av);
  }

  float attn = fmaxf(av, 0.f) + log1pf(expf(-fabsf(av)));   // softplus
  float dist = (lane < NS-1) ? (dval(lane+1) - dv) : 1e10f;
  float alpha = 1.0f - expf(-attn*dist);

  // inclusive multiplicative scan of (1-alpha+1e-6), shifted -> transmittance
  float fac = 1.0f - alpha + 1e-6f;
  float scan = fac;
  #pragma unroll
  for (int m=1; m<64; m<<=1){
    float up = __shfl_up(scan, m, 64);
    if (lane >= m) scan *= up;
  }
  float T = __shfl_up(scan, 1, 64);
  if (lane == 0) T = 1.0f;
  float wgt = T * alpha;

  float delf = fminf(fmaxf(rintf(sqrtf(dd2)*16000.0f/343.0f), 0.f), 511.f);

  const int bsid = b*NS + lane;
  const int o2 = bsid*RAYS + r;
  w_arr[o2] = wgt;
  delay_arr[o2] = (int)delf;

  // quartered store: quarter p -> [p][bsid][r][16] halves (32 B per quarter)
  #pragma unroll
  for (int p=0; p<SPLIT; p++){
    uint4 v0, v1;
    v0.x = pk2(wgt*h[p*16+ 0], wgt*h[p*16+ 1]);
    v0.y = pk2(wgt*h[p*16+ 2], wgt*h[p*16+ 3]);
    v0.z = pk2(wgt*h[p*16+ 4], wgt*h[p*16+ 5]);
    v0.w = pk2(wgt*h[p*16+ 6], wgt*h[p*16+ 7]);
    v1.x = pk2(wgt*h[p*16+ 8], wgt*h[p*16+ 9]);
    v1.y = pk2(wgt*h[p*16+10], wgt*h[p*16+11]);
    v1.z = pk2(wgt*h[p*16+12], wgt*h[p*16+13]);
    v1.w = pk2(wgt*h[p*16+14], wgt*h[p*16+15]);
    uint4* dst = (uint4*)(wh + (((size_t)p*BS*NS + bsid)*RAYS + r)*16);
    dst[0] = v0; dst[1] = v1;
  }
}

// K2: per (b,s,p): coalesced b128 scatter of the contiguous 16-col slab into
// delay buckets, 2-pass blocked scan (32 segs x 16 rows), dot with W_sig
// chunk + mask + path loss, atomicAdd into g. (Proven 55.4us config, round 7.)
__global__ __launch_bounds__(512)
void k2_bucket(const __half* __restrict__ wh, const float* __restrict__ w_arr,
               const int* __restrict__ delay_arr,
               const float* __restrict__ W_sig, const float* __restrict__ b_sig,
               float* __restrict__ g)
{
  __shared__ float bucket[LSEQ][JC+1];   // col 16 = w column; 34,816 B
  __shared__ float part[32][JC+1];       // 2,176 B
  __shared__ int   delay_l[RAYS];        // 2,056 B
  __shared__ float w_l[RAYS];            // 2,056 B  (total ~41 KB)
  const int blk = blockIdx.x;
  const int bsid = blk / SPLIT, p = blk % SPLIT;
  const int tid = threadIdx.x;
  const int obase = bsid * RAYS;

  for (int i = tid; i < LSEQ*(JC+1); i += 512) (&bucket[0][0])[i] = 0.f;
  for (int i = tid; i < RAYS; i += 512){
    delay_l[i] = delay_arr[obase + i];
    if (p == 0) w_l[i] = w_arr[obase + i];
  }
  __syncthreads();

  // scatter: 1028 uint4s (2 per ray), 3 coalesced sweeps; 8 LDS atomics each
  {
    const uint4* whp = (const uint4*)(wh + ((size_t)p*BS*NS + bsid)*RAYS*16);
    #pragma unroll
    for (int i=0; i<3; i++){
      int idx = i*512 + tid;
      if (idx < RAYS*2){
        int r = idx >> 1, c8 = (idx & 1) << 3;
        uint4 v = whp[idx];
        int d = delay_l[r];
        float* brow = &bucket[d][c8];
        atomicAdd(&brow[0], __half2float(__ushort_as_half((ushort)(v.x & 0xFFFF))));
        atomicAdd(&brow[1], __half2float(__ushort_as_half((ushort)(v.x >> 16))));
        atomicAdd(&brow[2], __half2float(__ushort_as_half((ushort)(v.y & 0xFFFF))));
        atomicAdd(&brow[3], __half2float(__ushort_as_half((ushort)(v.y >> 16))));
        atomicAdd(&brow[4], __half2float(__ushort_as_half((ushort)(v.z & 0xFFFF))));
        atomicAdd(&brow[5], __half2float(__ushort_as_half((ushort)(v.z >> 16))));
        atomicAdd(&brow[6], __half2float(__ushort_as_half((ushort)(v.w & 0xFFFF))));
        atomicAdd(&brow[7], __half2float(__ushort_as_half((ushort)(v.w >> 16))));
        if (p == 0 && c8 == 0) atomicAdd(&bucket[d][JC], w_l[r]);
      }
    }
  }
  __syncthreads();

  // blocked inclusive scan: 32 segs x 16 rows (w col scanned by col==15, p==0)
  const int seg = tid >> 4, col = tid & 15, d0 = seg*16;
  {
    float run = 0.f;
    for (int k=0;k<16;k++){ run += bucket[d0+k][col]; bucket[d0+k][col] = run; }
    part[seg][col] = run;
    if (p == 0 && col == 15){
      float rw = 0.f;
      for (int k=0;k<16;k++){ rw += bucket[d0+k][JC]; bucket[d0+k][JC] = rw; }
      part[seg][JC] = rw;
    }
  }
  __syncthreads();
  {
    float off = 0.f;
    for (int t=0;t<seg;t++) off += part[t][col];
    for (int k=0;k<16;k++) bucket[d0+k][col] += off;
    if (p == 0 && col == 15){
      float ow = 0.f;
      for (int t=0;t<seg;t++) ow += part[t][JC];
      for (int k=0;k<16;k++) bucket[d0+k][JC] += ow;
    }
  }
  __syncthreads();

  // dot + mask + path loss -> atomicAdd into g[bsid][l]  (one l per thread)
  const int s = bsid % NS;
  const float dv = dval(s);
  const float shiftf = rintf((16000.0f*dv)/343.0f);
  const int shift = (int)shiftf;
  const int jbase = p*JC;
  {
    const int l = tid;
    float mt = (((float)(LSEQ-1-l)) - shiftf > 0.f) ? 1.f : 0.f;
    if (mt > 0.f){
      float acc = 0.f;
      #pragma unroll
      for (int jj=0;jj<JC;jj++) acc += bucket[l][jj] * W_sig[(jbase+jj)*LSEQ + l];
      if (p == 0) acc += b_sig[l] * bucket[l][JC];
      int pli = shift + l;
      if (pli < 4) pli = 5;                     // path_loss[:4] = path_loss[5]
      float ideal = ((float)pli/16000.0f)*343.0f;
      atomicAdd(&g[bsid*LSEQ + l], acc / (ideal + 0.001f));
    }
  }
}

// K3: per (bsid, grp): 512-pt DFT of g, 4 l-chunk waves x 64 bins. Inner loop
// uses a cubic-polynomial factorization per float4 (P = g0+g1 s+g2 s^2+g3 s^3,
// then acc += P*w, w *= s^4): 13 VALU / 4 elems vs 20 before; twiddle reseeded
// exactly every 32 steps. Bin 256 = alternating sum on grp 0, wave 1
// (validated in round-9 mono). atomicAdd into out.
__global__ __launch_bounds__(256)
void k3_dft(const float* __restrict__ g, float* __restrict__ out)
{
  __shared__ float4 gs4[LSEQ/4];
  __shared__ float red[4][64][2];
  const int blk = blockIdx.x;
  const int bsid = blk >> 2, grp = blk & 3;
  const int b = bsid / NS, s = bsid % NS;
  const int tid = threadIdx.x;
  const int c = tid >> 6, bl = tid & 63;         // c = l-chunk wave, bl = bin

  if (tid < LSEQ/4) gs4[tid] = ((const float4*)(g + bsid*LSEQ))[tid];
  __syncthreads();

  const int k = grp*64 + bl;
  float re = 0.f, im = 0.f;
  {
    // per-lane step s = W(k) = e^{-i*2pi*k/512}; powers via complex mul
    float s1, c1; sincosf(-(TWO_PI_F/512.0f)*(float)k, &s1, &c1);
    float c2 = c1*c1 - s1*s1,  s2 = 2.0f*c1*s1;
    float c3 = c1*c2 - s1*s2,  s3 = c1*s2 + s1*c2;
    float c4 = c2*c2 - s2*s2,  s4 = 2.0f*c2*s2;
    const int l0 = c*128;
    int t0 = (k*l0) & (LSEQ-1);
    float wi, wr; sincosf(-(TWO_PI_F/512.0f)*(float)t0, &wi, &wr);
    for (int q=0; q<32; q++){
      float4 gv = gs4[c*32 + q];                 // wave-uniform broadcast
      float pr = gv.x + gv.y*c1 + gv.z*c2 + gv.w*c3;
      float pi =        gv.y*s1 + gv.z*s2 + gv.w*s3;
      re = fmaf(pr, wr, re); re = fmaf(-pi, wi, re);
      im = fmaf(pr, wi, im); im = fmaf( pi, wr, im);
      float nr = wr*c4 - wi*s4;
      wi = fmaf(wr, s4, wi*c4);
      wr = nr;
    }
  }
  red[c][bl][0] = re; red[c][bl][1] = im;
  __syncthreads();

  const float cfrac = (16000.0f*dval(s))/343.0f; // fractional pts2rx_idx
  if (tid < 64){
    const int kk = grp*64 + tid;
    float rs = red[0][tid][0] + red[1][tid][0] + red[2][tid][0] + red[3][tid][0];
    float is = red[0][tid][1] + red[1][tid][1] + red[2][tid][1] + red[3][tid][1];
    float ang = -(TWO_PI_F/512.0f)*((float)kk*cfrac);
    float sp, cp; sincosf(ang, &sp, &cp);
    atomicAdd(&out[(b*NF + kk)*2],     rs*cp - is*sp);
    atomicAdd(&out[(b*NF + kk)*2 + 1], rs*sp + is*cp);
  } else if (grp == 0 && tid < 128){
    // bin 256 on wave 1: DFT_256(g) = sum_l (-1)^l g[l] (exact, real)
    int t = tid - 64;
    float4 a = gs4[t], bq = gs4[t+64];
    float alt = (a.x - a.y + a.z - a.w) + (bq.x - bq.y + bq.z - bq.w);
    #pragma unroll
    for (int m=32; m>=1; m>>=1) alt += __shfl_xor(alt, m, 64);
    if (t == 0){
      float ang = -(TWO_PI_F/512.0f)*(256.0f*cfrac);
      float sp, cp; sincosf(ang, &sp, &cp);
      atomicAdd(&out[(b*NF + 256)*2],     alt*cp);
      atomicAdd(&out[(b*NF + 256)*2 + 1], alt*sp);
    }
  }
}

extern "C" void kernel_launch(void* const* d_in, const int* in_sizes, int n_in,
                              void* d_out, int out_size, void* d_ws, size_t ws_size,
                              hipStream_t stream)
{
  const float* rays_o      = (const float*)d_in[0];
  const float* position_tx = (const float*)d_in[1];
  const float* W1          = (const float*)d_in[2];
  const float* b1          = (const float*)d_in[3];
  const float* w_attn      = (const float*)d_in[4];
  const float* W_sig       = (const float*)d_in[5];
  const float* b_sig       = (const float*)d_in[6];
  float* out = (float*)d_out;

  // workspace layout (~9.2 MB total)
  char* ws = (char*)d_ws;
  __half* wh       = (__half*)ws;                               // 4*128*514*16*2B = 8,421,376
  float* w_arr     = (float*)(ws + 8421376);                    // 263,168
  int*   delay_arr = (int*)  (ws + 8421376 + 263168);           // 263,168
  float* g         = (float*)(ws + 8421376 + 2*263168);         // 262,144

  k1_rays  <<<(BS*RAYS)/4, 256, 0, stream>>>(rays_o, position_tx, W1, b1, w_attn,
                                             wh, w_arr, delay_arr, g, out);
  k2_bucket<<<BS*NS*SPLIT, 512, 0, stream>>>(wh, w_arr, delay_arr, W_sig, b_sig, g);
  k3_dft   <<<BS*NS*4,     256, 0, stream>>>(g, out);
}